// Round 1
// baseline (773.650 us; speedup 1.0000x reference)
//
#include <hip/hip_runtime.h>

#define T_N 16
#define H_F 600
#define W_F 600
#define H_P 300
#define W_P 300
#define H_E 150
#define W_E 150
#define FLAT 180000
#define HID 256
#define KC 768

// ---------------- Encoder stage 1: conv 2->4 (3x3, zero-pad) + relu + 2x2 mean pool
__global__ __launch_bounds__(256) void k_e1(const float* __restrict__ x,
    const float* __restrict__ w, const float* __restrict__ b, float* __restrict__ p1) {
  int idx = blockIdx.x * 256 + threadIdx.x;
  const int total = T_N * H_P * W_P;
  if (idx >= total) return;
  int wo = idx % W_P; int ho = (idx / W_P) % H_P; int n = idx / (W_P * H_P);
  float patch[4][4][2];
#pragma unroll
  for (int yy = 0; yy < 4; ++yy) {
    int hy = 2 * ho - 1 + yy;
    bool hok = (hy >= 0 && hy < H_F);
#pragma unroll
    for (int xx = 0; xx < 4; ++xx) {
      int wx = 2 * wo - 1 + xx;
      if (hok && wx >= 0 && wx < W_F) {
        const float2 v = *(const float2*)&x[((size_t)(n * H_F + hy) * W_F + wx) * 2];
        patch[yy][xx][0] = v.x; patch[yy][xx][1] = v.y;
      } else { patch[yy][xx][0] = 0.f; patch[yy][xx][1] = 0.f; }
    }
  }
  float s[4] = {0.f, 0.f, 0.f, 0.f};
#pragma unroll
  for (int dh = 0; dh < 2; ++dh)
#pragma unroll
  for (int dw = 0; dw < 2; ++dw) {
#pragma unroll
    for (int o = 0; o < 4; ++o) {
      float c = b[o];
#pragma unroll
      for (int kh = 0; kh < 3; ++kh)
#pragma unroll
      for (int kw = 0; kw < 3; ++kw) {
        c += patch[dh + kh][dw + kw][0] * w[(o * 2 + 0) * 9 + kh * 3 + kw]
           + patch[dh + kh][dw + kw][1] * w[(o * 2 + 1) * 9 + kh * 3 + kw];
      }
      s[o] += fmaxf(c, 0.f);
    }
  }
#pragma unroll
  for (int o = 0; o < 4; ++o)
    p1[((size_t)(n * 4 + o) * H_P + ho) * W_P + wo] = 0.25f * s[o];
}

// ---------------- Encoder stage 2: conv 4->8 + relu + pool, then immediately project to vf (2ch).
// xe (8ch) is only ever consumed through to_w, so it never hits memory.
__global__ __launch_bounds__(256) void k_e2(const float* __restrict__ p1,
    const float* __restrict__ w, const float* __restrict__ b,
    const float* __restrict__ tw, const float* __restrict__ tb,
    float* __restrict__ vf) {
  int idx = blockIdx.x * 256 + threadIdx.x;
  const int total = T_N * H_E * W_E;
  if (idx >= total) return;
  int wo = idx % W_E; int ho = (idx / W_E) % H_E; int n = idx / (W_E * H_E);
  float patch[4][4][4];
#pragma unroll
  for (int yy = 0; yy < 4; ++yy) {
    int hy = 2 * ho - 1 + yy; bool hok = (hy >= 0 && hy < H_P);
#pragma unroll
    for (int xx = 0; xx < 4; ++xx) {
      int wx = 2 * wo - 1 + xx; bool ok = hok && wx >= 0 && wx < W_P;
#pragma unroll
      for (int ci = 0; ci < 4; ++ci)
        patch[yy][xx][ci] = ok ? p1[((size_t)(n * 4 + ci) * H_P + hy) * W_P + wx] : 0.f;
    }
  }
  float s[8] = {0, 0, 0, 0, 0, 0, 0, 0};
#pragma unroll
  for (int dh = 0; dh < 2; ++dh)
#pragma unroll
  for (int dw = 0; dw < 2; ++dw) {
#pragma unroll
    for (int o = 0; o < 8; ++o) {
      float c = b[o];
#pragma unroll
      for (int kh = 0; kh < 3; ++kh)
#pragma unroll
      for (int kw = 0; kw < 3; ++kw)
#pragma unroll
      for (int ci = 0; ci < 4; ++ci)
        c += patch[dh + kh][dw + kw][ci] * w[((o * 4 + ci) * 3 + kh) * 3 + kw];
      s[o] += fmaxf(c, 0.f);
    }
  }
  float v0 = tb[0], v1 = tb[1];
#pragma unroll
  for (int cch = 0; cch < 8; ++cch) {
    float xv = 0.25f * s[cch];
    v0 += xv * tw[cch];
    v1 += xv * tw[8 + cch];
  }
  vf[((size_t)(n * 2 + 0) * H_E + ho) * W_E + wo] = v0;
  vf[((size_t)(n * 2 + 1) * H_E + ho) * W_E + wo] = v1;
}

// ---------------- Physics step (periodic rolls)
__global__ __launch_bounds__(256) void k_phys(const float* __restrict__ vf,
    const float* __restrict__ cor_p, const float* __restrict__ visc_p,
    const float* __restrict__ fric_p, const float* __restrict__ dt_p,
    float* __restrict__ vp) {
  int idx = blockIdx.x * 256 + threadIdx.x;
  const int total = T_N * H_E * W_E;
  if (idx >= total) return;
  int wq = idx % W_E; int hq = (idx / W_E) % H_E; int n = idx / (W_E * H_E);
  int hp = (hq == H_E - 1) ? 0 : hq + 1, hm = (hq == 0) ? H_E - 1 : hq - 1;
  int wp = (wq == W_E - 1) ? 0 : wq + 1, wm = (wq == 0) ? W_E - 1 : wq - 1;
  const float* u = vf + (size_t)(n * 2 + 0) * H_E * W_E;
  const float* v = vf + (size_t)(n * 2 + 1) * H_E * W_E;
  float uc = u[hq * W_E + wq], vc = v[hq * W_E + wq];
  float u_e = u[hq * W_E + wp], u_w = u[hq * W_E + wm], u_s = u[hp * W_E + wq], u_n = u[hm * W_E + wq];
  float v_e = v[hq * W_E + wp], v_w = v[hq * W_E + wm], v_s = v[hp * W_E + wq], v_n = v[hm * W_E + wq];
  float cor = cor_p[0], visc = visc_p[0], fric = fric_p[0], dt = dt_p[0];
  float du_dx = 0.5f * (u_e - u_w), du_dy = 0.5f * (u_s - u_n);
  float dv_dx = 0.5f * (v_e - v_w), dv_dy = 0.5f * (v_s - v_n);
  float lap_u = u_w + u_e + u_n + u_s - 4.f * uc;
  float lap_v = v_w + v_e + v_n + v_s - 4.f * vc;
  float du = -(uc * du_dx + vc * du_dy) + cor * vc + visc * lap_u - fric * uc;
  float dv = -(uc * dv_dx + vc * dv_dy) - cor * uc + visc * lap_v - fric * vc;
  vp[(size_t)(n * 2 + 0) * H_E * W_E + hq * W_E + wq] = uc + dt * du;
  vp[(size_t)(n * 2 + 1) * H_E * W_E + hq * W_E + wq] = vc + dt * dv;
}

// ---------------- Correction conv 1: 2->16, relu
__global__ __launch_bounds__(256) void k_corr1(const float* __restrict__ vp,
    const float* __restrict__ w, const float* __restrict__ b, float* __restrict__ c1) {
  int idx = blockIdx.x * 256 + threadIdx.x;
  const int total = T_N * H_E * W_E;
  if (idx >= total) return;
  int wq = idx % W_E; int hq = (idx / W_E) % H_E; int n = idx / (W_E * H_E);
  float acc[16];
#pragma unroll
  for (int o = 0; o < 16; ++o) acc[o] = b[o];
#pragma unroll
  for (int i = 0; i < 2; ++i) {
    const float* src = vp + (size_t)(n * 2 + i) * H_E * W_E;
#pragma unroll
    for (int kh = 0; kh < 3; ++kh) {
      int hy = hq + kh - 1; if (hy < 0 || hy >= H_E) continue;
#pragma unroll
      for (int kw = 0; kw < 3; ++kw) {
        int wx = wq + kw - 1; if (wx < 0 || wx >= W_E) continue;
        float vv = src[hy * W_E + wx];
#pragma unroll
        for (int o = 0; o < 16; ++o) acc[o] += vv * w[((o * 2 + i) * 3 + kh) * 3 + kw];
      }
    }
  }
#pragma unroll
  for (int o = 0; o < 16; ++o)
    c1[((size_t)(n * 16 + o) * H_E + hq) * W_E + wq] = fmaxf(acc[o], 0.f);
}

// ---------------- Correction conv 2 (16->2) + gated update + from_w projection -> feat
__global__ __launch_bounds__(256) void k_corr2feat(const float* __restrict__ c1,
    const float* __restrict__ w, const float* __restrict__ b,
    const float* __restrict__ vp, const float* __restrict__ pw,
    const float* __restrict__ fw, const float* __restrict__ fb,
    float* __restrict__ feat) {
  int idx = blockIdx.x * 256 + threadIdx.x;
  const int total = T_N * H_E * W_E;
  if (idx >= total) return;
  int wq = idx % W_E; int hq = (idx / W_E) % H_E; int n = idx / (W_E * H_E);
  float a0 = b[0], a1 = b[1];
#pragma unroll
  for (int kh = 0; kh < 3; ++kh) {
    int hy = hq + kh - 1; if (hy < 0 || hy >= H_E) continue;
#pragma unroll
    for (int kw = 0; kw < 3; ++kw) {
      int wx = wq + kw - 1; if (wx < 0 || wx >= W_E) continue;
      const float* src = c1 + (size_t)n * 16 * H_E * W_E + hy * W_E + wx;
#pragma unroll
      for (int i = 0; i < 16; ++i) {
        float vv = src[(size_t)i * H_E * W_E];
        a0 += vv * w[(i * 3 + kh) * 3 + kw];
        a1 += vv * w[((16 + i) * 3 + kh) * 3 + kw];
      }
    }
  }
  float s = 1.f / (1.f + expf(-pw[0]));
  float g = 1.f - s;   // updated = vp + (1-s)*corr
  float uc = vp[(size_t)(n * 2 + 0) * H_E * W_E + hq * W_E + wq];
  float vc = vp[(size_t)(n * 2 + 1) * H_E * W_E + hq * W_E + wq];
  float uu = uc + g * a0, vv2 = vc + g * a1;
#pragma unroll
  for (int o = 0; o < 8; ++o)
    feat[((size_t)(n * 8 + o) * H_E + hq) * W_E + wq] = fb[o] + fw[o * 2 + 0] * uu + fw[o * 2 + 1] * vv2;
}

// ---------------- zero helper (a_buf is atomic-accumulated)
__global__ void k_zero(float* __restrict__ p, int nfl) {
  int i = blockIdx.x * 256 + threadIdx.x;
  if (i < nfl) p[i] = 0.f;
}

// ---------------- GEMM1: a[r][t] = sum_k W_in[r][k] * feat[t][k]   (256 x 180000 x 16)
// lane = (tq = lane>>4 : 4 t's, is = lane&15 : k-slice). Split-K atomics into abuf.
__global__ __launch_bounds__(256) void k_gemm1(const float* __restrict__ Wg,
    const float* __restrict__ featg, float* __restrict__ abuf) {
  __shared__ float fs[KC][20];   // [k][t] padded: 16B-aligned b128 reads at t-quad
  int kt = blockIdx.x, rg = blockIdx.y;
  int k0 = kt * KC;
  int kc = FLAT - k0; if (kc > KC) kc = KC;
  int tid = threadIdx.x;
  for (int t = 0; t < 16; ++t) {
#pragma unroll
    for (int j = 0; j < 3; ++j) {
      int ii = j * 256 + tid;
      fs[ii][t] = (ii < kc) ? featg[(size_t)t * FLAT + k0 + ii] : 0.f;
    }
  }
  __syncthreads();
  int lane = tid & 63, wv = tid >> 6;
  int tq = lane >> 4, is = lane & 15;
  int row0 = rg * 64 + wv * 16;
  int njj = (kc + 63) >> 6;
#pragma unroll 1
  for (int g = 0; g < 2; ++g) {
    int rbase = row0 + g * 8;
    float acc[8][4];
#pragma unroll
    for (int r = 0; r < 8; ++r)
#pragma unroll
      for (int t2 = 0; t2 < 4; ++t2) acc[r][t2] = 0.f;
    const float* wrow = Wg + (size_t)rbase * FLAT + k0;
    for (int jj = 0; jj < njj; ++jj) {
      int kk = jj * 64 + is * 4;
      float wreg[8][4];
      if (kk < kc) {
#pragma unroll
        for (int r = 0; r < 8; ++r) {
          float4 t4 = *(const float4*)(wrow + (size_t)r * FLAT + kk);
          wreg[r][0] = t4.x; wreg[r][1] = t4.y; wreg[r][2] = t4.z; wreg[r][3] = t4.w;
        }
      } else {
#pragma unroll
        for (int r = 0; r < 8; ++r) { wreg[r][0] = 0; wreg[r][1] = 0; wreg[r][2] = 0; wreg[r][3] = 0; }
      }
#pragma unroll
      for (int dk = 0; dk < 4; ++dk) {
        float4 f4 = *(const float4*)&fs[jj * 64 + is * 4 + dk][tq * 4];
        float fr[4] = {f4.x, f4.y, f4.z, f4.w};
#pragma unroll
        for (int r = 0; r < 8; ++r)
#pragma unroll
          for (int t2 = 0; t2 < 4; ++t2) acc[r][t2] += wreg[r][dk] * fr[t2];
      }
    }
#pragma unroll
    for (int off = 1; off < 16; off <<= 1)
#pragma unroll
      for (int r = 0; r < 8; ++r)
#pragma unroll
        for (int t2 = 0; t2 < 4; ++t2)
          acc[r][t2] += __shfl_xor(acc[r][t2], off, 64);
    if (is == 0) {
#pragma unroll
      for (int r = 0; r < 8; ++r)
#pragma unroll
        for (int t2 = 0; t2 < 4; ++t2)
          atomicAdd(&abuf[(rbase + r) * 16 + tq * 4 + t2], acc[r][t2]);
    }
  }
}

// ---------------- Recurrence: h_t = tanh(a_t + W_in_b + W_hid h_{t-1} + W_hid_b), 16 steps, 1 block
__global__ __launch_bounds__(1024) void k_rec(const float* __restrict__ Wh,
    const float* __restrict__ Wib, const float* __restrict__ Whb,
    const float* __restrict__ abuf, float* __restrict__ hall) {
  __shared__ float hbuf[2][HID];
  __shared__ float part[4][HID];
  int tid = threadIdx.x;
  int i = tid & 255, sl = tid >> 8;
  if (tid < HID) hbuf[0][tid] = 0.f;
  __syncthreads();
  int cur = 0;
  for (int t = 0; t < 16; ++t) {
    const float* wr = Wh + (size_t)i * HID + sl * 64;
    float p = 0.f;
#pragma unroll
    for (int j = 0; j < 16; ++j) {
      float4 w4 = *(const float4*)&wr[j * 4];
      float4 h4 = *(const float4*)&hbuf[cur][sl * 64 + j * 4];
      p += w4.x * h4.x + w4.y * h4.y + w4.z * h4.z + w4.w * h4.w;
    }
    part[sl][i] = p;
    __syncthreads();
    if (tid < HID) {
      float tot = part[0][tid] + part[1][tid] + part[2][tid] + part[3][tid]
                + abuf[tid * 16 + t] + Wib[tid] + Whb[tid];
      float hn = tanhf(tot);
      hbuf[cur ^ 1][tid] = hn;
      hall[t * HID + tid] = hn;
    }
    __syncthreads();
    cur ^= 1;
  }
}

// ---------------- GEMM2: outs[t][k] = feat[t][k] + 0.1*(W_out[k].h_t + W_out_b[k])
// h (16x256) lives fully in registers per lane; coalesced W_out stream; LDS transpose for writes.
__global__ __launch_bounds__(256) void k_gemm2(const float* __restrict__ Wo,
    const float* __restrict__ Wob, const float* __restrict__ hall,
    const float* __restrict__ featg, float* __restrict__ outs) {
  __shared__ float tile[16][68];
  int kb = blockIdx.x * 64;
  int tid = threadIdx.x;
  int lane = tid & 63, wv = tid >> 6;
  int tq = lane >> 4, is = lane & 15;
  float hreg[4][4][4];   // [tt][jj][dk]
#pragma unroll
  for (int tt = 0; tt < 4; ++tt)
#pragma unroll
    for (int jj = 0; jj < 4; ++jj) {
      float4 h4 = *(const float4*)&hall[(tq * 4 + tt) * HID + jj * 64 + is * 4];
      hreg[tt][jj][0] = h4.x; hreg[tt][jj][1] = h4.y; hreg[tt][jj][2] = h4.z; hreg[tt][jj][3] = h4.w;
    }
  for (int rr = 0; rr < 16; ++rr) {
    int k = kb + wv * 16 + rr;
    float acc[4] = {0, 0, 0, 0};
    if (k < FLAT) {
      const float* wr = Wo + (size_t)k * HID;
#pragma unroll
      for (int jj = 0; jj < 4; ++jj) {
        float4 w4 = *(const float4*)&wr[jj * 64 + is * 4];
        float wv4[4] = {w4.x, w4.y, w4.z, w4.w};
#pragma unroll
        for (int dk = 0; dk < 4; ++dk)
#pragma unroll
          for (int tt = 0; tt < 4; ++tt)
            acc[tt] += wv4[dk] * hreg[tt][jj][dk];
      }
    }
#pragma unroll
    for (int off = 1; off < 16; off <<= 1)
#pragma unroll
      for (int tt = 0; tt < 4; ++tt)
        acc[tt] += __shfl_xor(acc[tt], off, 64);
    if (is == 0 && k < FLAT) {
#pragma unroll
      for (int tt = 0; tt < 4; ++tt)
        tile[tq * 4 + tt][wv * 16 + rr] = acc[tt];
    }
  }
  __syncthreads();
#pragma unroll
  for (int rep = 0; rep < 4; ++rep) {
    int id2 = rep * 256 + tid;
    int t = id2 >> 6, c = id2 & 63;
    int k = kb + c;
    if (k < FLAT)
      outs[(size_t)t * FLAT + k] = featg[(size_t)t * FLAT + k] + 0.1f * (tile[t][c] + Wob[k]);
  }
}

// ---------------- Decoder deconv1 (8->4, x2 up) + relu, one thread per output pixel
__global__ __launch_bounds__(256) void k_d1(const float* __restrict__ outs,
    const float* __restrict__ w, const float* __restrict__ b, float* __restrict__ d1) {
  int idx = blockIdx.x * 256 + threadIdx.x;
  const int total = T_N * H_P * W_P;
  if (idx >= total) return;
  int w2 = idx % W_P, h2 = (idx / W_P) % H_P, n = idx / (W_P * H_P);
  int hs = h2 >> 1, ws = w2 >> 1, p = h2 & 1, q = w2 & 1;
  const float* src = outs + (size_t)n * FLAT + hs * W_E + ws;
  float in8[8];
#pragma unroll
  for (int c = 0; c < 8; ++c) in8[c] = src[(size_t)c * H_E * W_E];
#pragma unroll
  for (int o = 0; o < 4; ++o) {
    float val = b[o];
#pragma unroll
    for (int i2 = 0; i2 < 8; ++i2)
      val += in8[i2] * w[((i2 * 4 + o) * 2 + p) * 2 + q];
    d1[((size_t)(n * 4 + o) * H_P + h2) * W_P + w2] = fmaxf(val, 0.f);
  }
}

// ---------------- Decoder deconv2 (4->2) + relu fused with final conv 3x3 (2->2) + NHWC write
__global__ __launch_bounds__(256) void k_d2cf(const float* __restrict__ d1,
    const float* __restrict__ w2, const float* __restrict__ b2,
    const float* __restrict__ cw, const float* __restrict__ cb,
    float* __restrict__ out) {
  int idx = blockIdx.x * 256 + threadIdx.x;
  const int total = T_N * H_F * W_F;
  if (idx >= total) return;
  int wq = idx % W_F, hq = (idx / W_F) % H_F, n = idx / (W_F * H_F);
  float o0 = cb[0], o1 = cb[1];
#pragma unroll
  for (int kh = 0; kh < 3; ++kh) {
    int hh = hq + kh - 1; if (hh < 0 || hh >= H_F) continue;
#pragma unroll
    for (int kw = 0; kw < 3; ++kw) {
      int wwx = wq + kw - 1; if (wwx < 0 || wwx >= W_F) continue;
      int hs = hh >> 1, ws = wwx >> 1, p = hh & 1, q = wwx & 1;
      const float* src = d1 + (size_t)n * 4 * H_P * W_P + hs * W_P + ws;
      float a0 = b2[0], a1 = b2[1];
#pragma unroll
      for (int i2 = 0; i2 < 4; ++i2) {
        float dv = src[(size_t)i2 * H_P * W_P];
        a0 += dv * w2[((i2 * 2 + 0) * 2 + p) * 2 + q];
        a1 += dv * w2[((i2 * 2 + 1) * 2 + p) * 2 + q];
      }
      a0 = fmaxf(a0, 0.f); a1 = fmaxf(a1, 0.f);
      o0 += a0 * cw[0 * 9 + kh * 3 + kw] + a1 * cw[1 * 9 + kh * 3 + kw];
      o1 += a0 * cw[2 * 9 + kh * 3 + kw] + a1 * cw[3 * 9 + kh * 3 + kw];
    }
  }
  *(float2*)&out[(size_t)idx * 2] = make_float2(o0, o1);
}

extern "C" void kernel_launch(void* const* d_in, const int* in_sizes, int n_in,
                              void* d_out, int out_size, void* d_ws, size_t ws_size,
                              hipStream_t stream) {
  (void)in_sizes; (void)n_in; (void)out_size; (void)ws_size;
  const float* x    = (const float*)d_in[0];
  const float* c1w  = (const float*)d_in[1];
  const float* c1b  = (const float*)d_in[2];
  const float* c2w  = (const float*)d_in[3];
  const float* c2b  = (const float*)d_in[4];
  const float* tow  = (const float*)d_in[5];
  const float* tob  = (const float*)d_in[6];
  const float* cor  = (const float*)d_in[7];
  const float* visc = (const float*)d_in[8];
  const float* fric = (const float*)d_in[9];
  const float* dtp  = (const float*)d_in[10];
  const float* pw   = (const float*)d_in[11];
  const float* cr1w = (const float*)d_in[12];
  const float* cr1b = (const float*)d_in[13];
  const float* cr2w = (const float*)d_in[14];
  const float* cr2b = (const float*)d_in[15];
  const float* fw   = (const float*)d_in[16];
  const float* fb   = (const float*)d_in[17];
  const float* Wi   = (const float*)d_in[18];
  const float* Wib  = (const float*)d_in[19];
  const float* Wh   = (const float*)d_in[20];
  const float* Whb  = (const float*)d_in[21];
  const float* Wo   = (const float*)d_in[22];
  const float* Wob  = (const float*)d_in[23];
  const float* d1w  = (const float*)d_in[24];
  const float* d1b  = (const float*)d_in[25];
  const float* d2w  = (const float*)d_in[26];
  const float* d2b  = (const float*)d_in[27];
  const float* cfw  = (const float*)d_in[28];
  const float* cfb  = (const float*)d_in[29];

  float* ws_f  = (float*)d_ws;
  float* p1    = ws_f;                  // 5,760,000 (reused as d1 later)
  float* vf    = p1 + 5760000;          //   720,000
  float* vp    = vf + 720000;           //   720,000
  float* c1buf = vp + 720000;           // 5,760,000
  float* featb = c1buf + 5760000;       // 2,880,000
  float* outsb = featb + 2880000;       // 2,880,000
  float* abuf  = outsb + 2880000;       //     4,096
  float* hall  = abuf + 4096;           //     4,096
  float* out   = (float*)d_out;

  k_zero<<<16, 256, 0, stream>>>(abuf, 4096);
  k_e1<<<5625, 256, 0, stream>>>(x, c1w, c1b, p1);
  k_e2<<<1407, 256, 0, stream>>>(p1, c2w, c2b, tow, tob, vf);
  k_phys<<<1407, 256, 0, stream>>>(vf, cor, visc, fric, dtp, vp);
  k_corr1<<<1407, 256, 0, stream>>>(vp, cr1w, cr1b, c1buf);
  k_corr2feat<<<1407, 256, 0, stream>>>(c1buf, cr2w, cr2b, vp, pw, fw, fb, featb);
  dim3 g1((FLAT + KC - 1) / KC, 4);
  k_gemm1<<<g1, 256, 0, stream>>>(Wi, featb, abuf);
  k_rec<<<1, 1024, 0, stream>>>(Wh, Wib, Whb, abuf, hall);
  k_gemm2<<<(FLAT + 63) / 64, 256, 0, stream>>>(Wo, Wob, hall, featb, outsb);
  k_d1<<<5625, 256, 0, stream>>>(outsb, d1w, d1b, p1);
  k_d2cf<<<22500, 256, 0, stream>>>(p1, d2w, d2b, cfw, cfb, out);
}